// Round 13
// baseline (1461.794 us; speedup 1.0000x reference)
//
#include <hip/hip_runtime.h>
#include <hip/hip_bf16.h>
#include <math.h>
#include <stdint.h>

#define T_LEN 8192
#define RCH   512
#define SCH   256
#define QCH   256
#define ACH   28
#define NLAYER 30
#define KGATE 1088   // 512 tap0 + 512 tap1 + 64 aux (zero-padded from 28) = 17*64
#define KSR   512
#define KPOST 256
#define PSTR  1032   // LDS row stride (shorts) in pack_gated_lds: 1024 + 8 pad

typedef _Float16 f16x8 __attribute__((ext_vector_type(8)));
typedef float    f32x4 __attribute__((ext_vector_type(4)));

#define SB0() __builtin_amdgcn_sched_barrier(0)

static __device__ __forceinline__ unsigned short f2h(float v) {
    _Float16 h = (_Float16)v;                 // RTN
    return *reinterpret_cast<unsigned short*>(&h);
}

// fast sigmoid: v_exp_f32 + rcp
static __device__ __forceinline__ float fsig(float x) {
    return __builtin_amdgcn_rcpf(1.f + __expf(-x));
}

// global -> LDS direct copy, 16B per lane, LDS dest wave-uniform base
#define G2L(SRC, DST) __builtin_amdgcn_global_load_lds(                        \
    (__attribute__((address_space(1))) void*)(const void*)(SRC),              \
    (__attribute__((address_space(3))) void*)(void*)(DST), 16, 0, 0)

// ---------------------------------------------------------------------------
// Gate dilated-tap pack via LDS transpose: one block per (mt, layer).
// Read: two CONTIGUOUS 32KB regions (Wds rows mt*8..+8, Wdt same) coalesced;
// convert to fp16 into LDS [16 m][1024+pad] = [tap0 512 | tap1 512].
// Write: 32 fragment-order tiles, each 64 threads x 16B = 1KB contiguous.
// Fragment map: dst[(mt*34+kt)*512 + lane*8 + i] =
//   A[mt*16+(lane&15)][kt*32+(lane>>4)*8+i]; A row 2r = Wds ch r, 2r+1 = Wdt.
__global__ void pack_gated_lds(const float* __restrict__ Wds,
                               const float* __restrict__ Wdt,
                               unsigned short* __restrict__ dst) {
    __shared__ unsigned short L[16 * PSTR];            // 33 KB
    const int l  = blockIdx.y;
    const int mt = blockIdx.x;                         // 0..63
    const int t  = threadIdx.x;

    const float* S0 = Wds + (size_t)l * RCH * RCH * 2 + (size_t)mt * 8 * 1024;
    const float* S1 = Wdt + (size_t)l * RCH * RCH * 2 + (size_t)mt * 8 * 1024;

    #pragma unroll
    for (int br = 0; br < 2; ++br) {
        const float* S = br ? S1 : S0;
        #pragma unroll
        for (int r = 0; r < 8; ++r) {
            int fidx = (r * 256 + t) * 4;              // 0..32764, coalesced
            float4 v = *(const float4*)(S + fidx);
            int ch_off = fidx >> 10;                   // row 0..7
            int k = (fidx & 1023) >> 1;                // even k; row floats = (k,t0),(k,t1),...
            int g = ch_off * 2 + br;                   // interleaved m-row
            unsigned int p0 = (unsigned int)f2h(v.x) | ((unsigned int)f2h(v.z) << 16);
            unsigned int p1 = (unsigned int)f2h(v.y) | ((unsigned int)f2h(v.w) << 16);
            *(unsigned int*)&L[g * PSTR + k]       = p0;   // tap0: k, k+1
            *(unsigned int*)&L[g * PSTR + 512 + k] = p1;   // tap1: k, k+1
        }
    }
    __syncthreads();

    // 32 dilated tiles (kt 0..15 = tap0 windows, 16..31 = tap1 windows);
    // unified LDS offset = kt*32 + (lane>>4)*8 (tap1 region starts at 512).
    size_t base = (size_t)l * 1024 * KGATE + (size_t)mt * 34 * 512;
    #pragma unroll
    for (int w = 0; w < 8; ++w) {
        int idx  = w * 256 + t;                        // 0..2047
        int kt   = idx >> 6;                           // 0..31
        int lane = idx & 63;
        int g    = lane & 15;
        int koff = kt * 32 + (lane >> 4) * 8;
        uint4 v = *(uint4*)&L[g * PSTR + koff];
        *(uint4*)&dst[base + (size_t)kt * 512 + lane * 8] = v;
    }
}

// Gate aux pack (tiles 32,33 of each mt): 1024 m x 8 kgroups = 8192 thr.
__global__ void pack_gatea_v(const float* __restrict__ Was,
                             const float* __restrict__ Wat,
                             unsigned short* __restrict__ dst) {
    int l = blockIdx.y;
    int c = blockIdx.x * 256 + threadIdx.x;   // grid.x = 32
    int mlow = c & 15;
    int kg   = (c >> 4) & 7;                  // a0 = kg*8
    int mhi  = c >> 7;                        // 0..63
    int m  = mhi * 16 + mlow;
    int a0 = kg * 8;
    int br = m & 1, ch = m >> 1;
    const float* Wa = (br ? Wat : Was) + (size_t)l * RCH * ACH + (size_t)ch * ACH;
    unsigned short o[8];
    #pragma unroll
    for (int i = 0; i < 8; ++i)
        o[i] = (a0 + i < ACH) ? f2h(Wa[a0 + i]) : (unsigned short)0;
    int mt   = m >> 4;
    int lane = ((a0 & 31) >> 3) * 16 + mlow;
    *(uint4*)&dst[(size_t)l * 1024 * KGATE
                  + (size_t)(mt * 34 + 32 + (a0 >> 5)) * 512 + lane * 8] = *(uint4*)o;
}

__global__ void pack_sr_v(const float* __restrict__ Wsk,
                          const float* __restrict__ Wr,
                          unsigned short* __restrict__ dst) {
    int l = blockIdx.y;
    int c = blockIdx.x * 256 + threadIdx.x;   // grid.x = 192
    int tile = c >> 6, lane = c & 63;
    int mt = tile >> 4, kt = tile & 15;       // KT32 = 16
    int m  = mt * 16 + (lane & 15);
    int k0 = kt * 32 + (lane >> 4) * 8;
    const float* row = (m < SCH) ? (Wsk + (size_t)l * SCH * RCH + (size_t)m * 512)
                                 : (Wr  + (size_t)l * RCH * RCH + (size_t)(m - SCH) * 512);
    float4 v0 = *(const float4*)(row + k0);
    float4 v1 = *(const float4*)(row + k0 + 4);
    unsigned short o[8] = { f2h(v0.x), f2h(v0.y), f2h(v0.z), f2h(v0.w),
                            f2h(v1.x), f2h(v1.y), f2h(v1.z), f2h(v1.w) };
    *(uint4*)&dst[(size_t)l * 768 * KSR + (size_t)tile * 512 + lane * 8] = *(uint4*)o;
}

__global__ void pack_post_v(const float* __restrict__ W,
                            unsigned short* __restrict__ dst) {
    int c = blockIdx.x * 256 + threadIdx.x;   // grid = 32
    int tile = c >> 6, lane = c & 63;
    int mt = tile >> 3, kt = tile & 7;        // KT32 = 8
    int m  = mt * 16 + (lane & 15);
    int k0 = kt * 32 + (lane >> 4) * 8;
    float4 v0 = *(const float4*)(W + (size_t)m * 256 + k0);
    float4 v1 = *(const float4*)(W + (size_t)m * 256 + k0 + 4);
    unsigned short o[8] = { f2h(v0.x), f2h(v0.y), f2h(v0.z), f2h(v0.w),
                            f2h(v1.x), f2h(v1.y), f2h(v1.z), f2h(v1.w) };
    *(uint4*)&dst[(size_t)tile * 512 + lane * 8] = *(uint4*)o;
}

// Wc [R][Q][2] -> WcT [Q][2][R]; 512*512/256 = 1024 WGs
__global__ void transpose_wc(const float* __restrict__ Wc,
                             float* __restrict__ WcT) {
    int idx = blockIdx.x * 256 + threadIdx.x;
    int r = idx >> 9;
    int qt = idx & 511;
    int q = qt >> 1, tap = qt & 1;
    WcT[(size_t)q * 1024 + tap * 512 + r] = Wc[(size_t)r * 512 + qt];
}

// ---------------------------------------------------------------------------
// embed: one wave per t; 8 channels/thread; coalesced via WcT.
__global__ void embed_v(const int* __restrict__ x,
                        const float* __restrict__ WcT,
                        const float* __restrict__ bc,
                        float* __restrict__ out_tm,
                        unsigned short* __restrict__ outhf) {
    int idx = blockIdx.x * 256 + threadIdx.x; // 2048 WGs
    int t = idx >> 6, rc = (idx & 63) * 8;
    int x1 = x[t];
    const float* w1 = WcT + (size_t)x1 * 1024 + 512 + rc;
    float4 a = *(const float4*)w1;
    float4 b = *(const float4*)(w1 + 4);
    float4 c0 = *(const float4*)(bc + rc);
    float4 c1 = *(const float4*)(bc + rc + 4);
    a.x += c0.x; a.y += c0.y; a.z += c0.z; a.w += c0.w;
    b.x += c1.x; b.y += c1.y; b.z += c1.z; b.w += c1.w;
    if (t > 0) {
        const float* w0 = WcT + (size_t)x[t - 1] * 1024 + rc;
        float4 d0 = *(const float4*)w0;
        float4 d1 = *(const float4*)(w0 + 4);
        a.x += d0.x; a.y += d0.y; a.z += d0.z; a.w += d0.w;
        b.x += d1.x; b.y += d1.y; b.z += d1.z; b.w += d1.w;
    }
    size_t o = (size_t)t * 512 + rc;
    *(float4*)&out_tm[o] = a;
    *(float4*)&out_tm[o + 4] = b;
    unsigned short p[8] = { f2h(a.x), f2h(a.y), f2h(a.z), f2h(a.w),
                            f2h(b.x), f2h(b.y), f2h(b.z), f2h(b.w) };
    *(uint4*)&outhf[o + 512 * 512] = *(uint4*)p;
}

// h -> time-major fp16 [8192][64], zero-padded channels 28..63
__global__ void packh_kernel(const float* __restrict__ h,
                             unsigned short* __restrict__ h_tm) {
    int idx = blockIdx.x * 256 + threadIdx.x;
    int t = idx >> 6, a = idx & 63;
    h_tm[idx] = f2h(a < ACH ? h[(size_t)a * T_LEN + t] : 0.f);
}

// relu(skip) -> fp16, 8/thread
__global__ void reluconv_v(const float* __restrict__ skip,
                           unsigned short* __restrict__ dst) {
    int idx = (blockIdx.x * 256 + threadIdx.x) * 8;
    float4 v0 = *(const float4*)(skip + idx);
    float4 v1 = *(const float4*)(skip + idx + 4);
    unsigned short o[8] = { f2h(fmaxf(v0.x, 0.f)), f2h(fmaxf(v0.y, 0.f)),
                            f2h(fmaxf(v0.z, 0.f)), f2h(fmaxf(v0.w, 0.f)),
                            f2h(fmaxf(v1.x, 0.f)), f2h(fmaxf(v1.y, 0.f)),
                            f2h(fmaxf(v1.z, 0.f)), f2h(fmaxf(v1.w, 0.f)) };
    *(uint4*)&dst[idx] = *(uint4*)o;
}

// ---------------------------------------------------------------------------
// MFMA GEMM, tile 128(M) x 128(N=time), BK=64, 4 waves in 4m x 1n layout
// (R12 structure, proven 1427us) + OCCUPANCY 3 blocks/CU:
//   - __launch_bounds__(256, 3): cap VGPR at ~168 -> 3 waves/SIMD
//   - B fragments STREAMED 2-at-a-time inside the MFMA loop (kills bfr[8][2]'s
//     64 VGPRs; compiler emits fine-grained lgkmcnt per ds_read->MFMA dep).
// Pipeline per step (pinned order, R8-proven):
//   [4x G2L stage(kt+1)] SB0 [2x afr(kt+1)] SB0
//   [stream-bfr + setprio(1) MFMA(kt) setprio(0)]
//   SB0 "s_waitcnt vmcnt(2) lgkmcnt(0)" SB0 s_barrier
// FIFO at tail: [G2L(kt+1)x4 oldest | afr(kt+1)x2] -> vmcnt(2) retires exactly
// the G2Ls; afr(kt+1) crosses the barrier. lgkmcnt(0) closes rule-#18 hazard.
// XOR-swizzled LDS (both-sides, rule #21). Bijective XCD swizzle.
template<int MODE, int KT64, int MB>
__global__ __launch_bounds__(256, 3) void mfma_gemm(
    const unsigned short* __restrict__ Apk,
    const unsigned short* __restrict__ B0,
    const unsigned short* __restrict__ B2,
    const float* __restrict__ bias0, const float* __restrict__ bias1,
    const float* __restrict__ bias2, const float* __restrict__ bias3,
    float* __restrict__ O0, float* __restrict__ O1,
    unsigned short* __restrict__ OB, int dil)
{
    constexpr int KT32 = KT64 * 2;
    constexpr int NWG = MB * 64;
    constexpr int CPX = NWG / 8;

    __shared__ unsigned short Bsm[2][128 * 64];       // 2 x 16 KB

    const int tid  = threadIdx.x;
    const int lane = tid & 63, wave = tid >> 6;

    const int bid = blockIdx.x;
    const int swz = (bid & 7) * CPX + (bid >> 3);     // bijective XCD swizzle
    const int mb  = swz % MB;
    const int tb  = swz / MB;
    const int m0  = mb * 128;
    const int t0  = tb * 128;

    const int kc   = ((lane & 7) ^ (lane >> 3)) * 8;  // pre-swizzled source chunk
    const int rsub = lane >> 3;

    const size_t mt0 = (size_t)(mb * 8) + wave * 2;   // wave owns 2 mt (32 rows)

    f32x4 acc[2][8];
    #pragma unroll
    for (int a = 0; a < 2; ++a)
        #pragma unroll
        for (int b = 0; b < 8; ++b) acc[a][b] = (f32x4){0.f, 0.f, 0.f, 0.f};

    // afr[mi] packs both k-halves as 2 f16x8 (4 global loads total per step:
    // 2 per mi row-pair... kept as 2 dwordx4 loads per mt -> 2 loads/step here)
    f16x8 afrA[2][2], afrB[2][2];

    auto stage_tile = [&](int kt, int buf) {
        const int kb = kt * 64;
        #pragma unroll
        for (int j = 0; j < 4; ++j) {
            const int row = wave * 32 + j * 8 + rsub;
            const int tg  = t0 + row;
            const unsigned short* src;
            if constexpr (MODE == 0) {
                if (kb < 512)
                    src = B0 + (size_t)(512 + tg - dil) * 512 + kb + kc;
                else if (kb < 1024)
                    src = B0 + (size_t)(512 + tg) * 512 + (kb - 512) + kc;
                else
                    src = B2 + (size_t)tg * 64 + kc;
            } else if constexpr (MODE == 1) {
                src = B0 + (size_t)tg * 512 + kb + kc;
            } else {
                src = B0 + (size_t)tg * 256 + kb + kc;
            }
            G2L(src, &Bsm[buf][(wave * 4 + j) * 512]);
        }
    };

    auto load_afr = [&](int kt, f16x8 (&dst)[2][2]) {
        #pragma unroll
        for (int mi = 0; mi < 2; ++mi)
            #pragma unroll
            for (int ks = 0; ks < 2; ++ks)
                dst[mi][ks] = *(const f16x8*)(Apk +
                    ((mt0 + mi) * KT32 + (size_t)(kt * 2 + ks)) * 512 + lane * 8);
    };

    // streamed-B MFMA: load 2 bfr regs per ni right before use (VGPR ~140)
    auto compute = [&](int buf, f16x8 (&A)[2][2]) {
        __builtin_amdgcn_s_setprio(1);
        #pragma unroll
        for (int ni = 0; ni < 8; ++ni) {
            const int trow = ni * 16 + (lane & 15);
            const int kch0 = lane >> 4;
            f16x8 b0 = *(const f16x8*)&Bsm[buf][trow * 64 + ((kch0    ) ^ (lane & 7)) * 8];
            f16x8 b1 = *(const f16x8*)&Bsm[buf][trow * 64 + ((kch0 + 4) ^ (lane & 7)) * 8];
            #pragma unroll
            for (int mi = 0; mi < 2; ++mi) {
                acc[mi][ni] = __builtin_amdgcn_mfma_f32_16x16x32_f16(
                    A[mi][0], b0, acc[mi][ni], 0, 0, 0);
                acc[mi][ni] = __builtin_amdgcn_mfma_f32_16x16x32_f16(
                    A[mi][1], b1, acc[mi][ni], 0, 0, 0);
            }
        }
        __builtin_amdgcn_s_setprio(0);
    };

    // prologue: [4 G2L tile0] SB0 [4 afr0 loads] SB0 vmcnt(4) barrier
    stage_tile(0, 0);
    SB0();
    load_afr(0, afrA);
    SB0();
    asm volatile("s_waitcnt vmcnt(4)" ::: "memory");
    SB0();
    __builtin_amdgcn_s_barrier();

    #pragma unroll
    for (int kt = 0; kt < KT64; ++kt) {
        const int cur = kt & 1;
        if (kt + 1 < KT64) {
            stage_tile(kt + 1, cur ^ 1);              // 4 G2L, oldest group
            SB0();
            if (cur) load_afr(kt + 1, afrA);          // 4 reg loads, cross barrier
            else     load_afr(kt + 1, afrB);
            SB0();
        }
        if (cur) compute(cur, afrB);
        else     compute(cur, afrA);
        if (kt + 1 < KT64) {
            SB0();
            asm volatile("s_waitcnt vmcnt(4) lgkmcnt(0)" ::: "memory");
            SB0();
            __builtin_amdgcn_s_barrier();
        }
    }

    // ---- epilogue ----
    const int rb0 = (lane >> 4) * 4;
    #pragma unroll
    for (int mi = 0; mi < 2; ++mi) {
        #pragma unroll
        for (int ni = 0; ni < 8; ++ni) {
            int m = m0 + wave * 32 + mi * 16 + rb0;   // multiple of 4
            int t = t0 + ni * 16 + (lane & 15);
            f32x4 v = acc[mi][ni];
            if constexpr (MODE == 0) {
                int c0 = m >> 1;                       // even
                float s0 = v.x + bias0[c0]     + bias2[c0];
                float tv0 = v.y + bias1[c0]     + bias3[c0];
                float s1 = v.z + bias0[c0 + 1] + bias2[c0 + 1];
                float tv1 = v.w + bias1[c0 + 1] + bias3[c0 + 1];
                // g = sigmoid(s) * tanh(t);  tanh(t) = 2*sigmoid(2t) - 1
                float g0 = fsig(s0) * (2.f * fsig(2.f * tv0) - 1.f);
                float g1 = fsig(s1) * (2.f * fsig(2.f * tv1) - 1.f);
                unsigned int p = (unsigned int)f2h(g0) | ((unsigned int)f2h(g1) << 16);
                *(unsigned int*)&OB[(size_t)t * 512 + c0] = p;
            } else if constexpr (MODE == 1) {
                if (m < SCH) {
                    float4* p = (float4*)&O0[(size_t)t * 256 + m];
                    float4 o = *p;
                    o.x += v.x + bias0[m + 0];
                    o.y += v.y + bias0[m + 1];
                    o.z += v.z + bias0[m + 2];
                    o.w += v.w + bias0[m + 3];
                    *p = o;
                } else {
                    int c = m - SCH;
                    float4* p = (float4*)&O1[(size_t)t * 512 + c];
                    float4 o = *p;
                    o.x += v.x + bias1[c + 0];
                    o.y += v.y + bias1[c + 1];
                    o.z += v.z + bias1[c + 2];
                    o.w += v.w + bias1[c + 3];
                    *p = o;
                    uint2 pk;
                    pk.x = (unsigned int)f2h(o.x) | ((unsigned int)f2h(o.y) << 16);
                    pk.y = (unsigned int)f2h(o.z) | ((unsigned int)f2h(o.w) << 16);
                    *(uint2*)&OB[(size_t)(512 + t) * 512 + c] = pk;
                }
            } else if constexpr (MODE == 2) {
                float o0 = fmaxf(v.x + bias0[m + 0], 0.f);
                float o1 = fmaxf(v.y + bias0[m + 1], 0.f);
                float o2 = fmaxf(v.z + bias0[m + 2], 0.f);
                float o3 = fmaxf(v.w + bias0[m + 3], 0.f);
                uint2 pk;
                pk.x = (unsigned int)f2h(o0) | ((unsigned int)f2h(o1) << 16);
                pk.y = (unsigned int)f2h(o2) | ((unsigned int)f2h(o3) << 16);
                *(uint2*)&OB[(size_t)t * 256 + m] = pk;
            } else {
                float4 o;
                o.x = v.x + bias0[m + 0];
                o.y = v.y + bias0[m + 1];
                o.z = v.z + bias0[m + 2];
                o.w = v.w + bias0[m + 3];
                *(float4*)&O0[(size_t)t * 256 + m] = o;
            }
        }
    }
}

// ---------------------------------------------------------------------------
extern "C" void kernel_launch(void* const* d_in, const int* in_sizes, int n_in,
                              void* d_out, int out_size, void* d_ws, size_t ws_size,
                              hipStream_t stream) {
    const int*   x   = (const int*)  d_in[0];
    const float* h   = (const float*)d_in[1];
    const float* Wc  = (const float*)d_in[2];
    const float* bc  = (const float*)d_in[3];
    const float* Wds = (const float*)d_in[4];
    const float* bds = (const float*)d_in[5];
    const float* Wdt = (const float*)d_in[6];
    const float* bdt = (const float*)d_in[7];
    const float* Was = (const float*)d_in[8];
    const float* bas = (const float*)d_in[9];
    const float* Wat = (const float*)d_in[10];
    const float* bat = (const float*)d_in[11];
    const float* Wsk = (const float*)d_in[12];
    const float* bsk = (const float*)d_in[13];
    const float* Wr  = (const float*)d_in[14];
    const float* br  = (const float*)d_in[15];
    const float* Wp1 = (const float*)d_in[16];
    const float* bp1 = (const float*)d_in[17];
    const float* Wp2 = (const float*)d_in[18];
    const float* bp2 = (const float*)d_in[19];
    float* dout = (float*)d_out;

    // ---- workspace layout (bytes) ----
    const size_t WG_EL  = (size_t)1024 * KGATE;
    const size_t WSR_EL = (size_t)768 * KSR;
    char* w = (char*)d_ws;
    float*          out_tm = (float*)w;               w += (size_t)T_LEN * 512 * 4;
    unsigned short* outhf  = (unsigned short*)w;      w += (size_t)(T_LEN + 512) * 512 * 2;
    unsigned short* g_tm   = (unsigned short*)w;      w += (size_t)T_LEN * 512 * 2;
    unsigned short* h_tm   = (unsigned short*)w;      w += (size_t)T_LEN * 64 * 2;
    unsigned short* skiphf = (unsigned short*)w;      w += (size_t)T_LEN * 256 * 2;
    unsigned short* o1hf   = (unsigned short*)w;      w += (size_t)T_LEN * 256 * 2;
    unsigned short* Wp1_pk = (unsigned short*)w;      w += (size_t)256 * 256 * 2;
    unsigned short* Wp2_pk = (unsigned short*)w;      w += (size_t)256 * 256 * 2;
    float*          WcT    = (float*)w;               w += (size_t)QCH * 2 * RCH * 4;   // 1 MB
    unsigned short* Wg_pk  = (unsigned short*)w;
    size_t used_base = (size_t)((char*)Wg_pk - (char*)d_ws);
    size_t need_bulk = used_base + (WG_EL + WSR_EL) * NLAYER * 2;
    const bool bulk = ws_size >= need_bulk;
    unsigned short* Wsr_pk = Wg_pk + (bulk ? WG_EL * NLAYER : WG_EL);
    float* skip = dout;                               // [8192][256] f32 accumulator

    hipMemsetAsync(skip, 0, (size_t)T_LEN * 256 * 4, stream);
    hipMemsetAsync(outhf, 0, (size_t)512 * 512 * 2, stream);

    transpose_wc<<<1024, 256, 0, stream>>>(Wc, WcT);
    embed_v<<<(T_LEN * 64) / 256, 256, 0, stream>>>(x, WcT, bc, out_tm, outhf);
    packh_kernel<<<(T_LEN * 64) / 256, 256, 0, stream>>>(h, h_tm);
    pack_post_v<<<32, 256, 0, stream>>>(Wp1, Wp1_pk);
    pack_post_v<<<32, 256, 0, stream>>>(Wp2, Wp2_pk);

    if (bulk) {
        pack_gated_lds<<<dim3(64, NLAYER), 256, 0, stream>>>(Wds, Wdt, Wg_pk);
        pack_gatea_v<<<dim3(32, NLAYER), 256, 0, stream>>>(Was, Wat, Wg_pk);
        pack_sr_v<<<dim3(192, NLAYER), 256, 0, stream>>>(Wsk, Wr, Wsr_pk);
    }

    for (int l = 0; l < NLAYER; ++l) {
        int dil = 1 << (l % 10);
        const unsigned short* wg;
        const unsigned short* wsr;
        if (bulk) {
            wg  = Wg_pk  + (size_t)l * WG_EL;
            wsr = Wsr_pk + (size_t)l * WSR_EL;
        } else {
            pack_gated_lds<<<dim3(64, 1), 256, 0, stream>>>(
                Wds + (size_t)l * RCH * RCH * 2, Wdt + (size_t)l * RCH * RCH * 2, Wg_pk);
            pack_gatea_v<<<dim3(32, 1), 256, 0, stream>>>(
                Was + (size_t)l * RCH * ACH, Wat + (size_t)l * RCH * ACH, Wg_pk);
            pack_sr_v<<<dim3(192, 1), 256, 0, stream>>>(
                Wsk + (size_t)l * SCH * RCH, Wr + (size_t)l * RCH * RCH, Wsr_pk);
            wg = Wg_pk; wsr = Wsr_pk;
        }
        mfma_gemm<0, KGATE / 64, 8><<<512, 256, 0, stream>>>(
            wg, outhf, h_tm,
            bds + (size_t)l * RCH, bdt + (size_t)l * RCH,
            bas + (size_t)l * RCH, bat + (size_t)l * RCH,
            nullptr, nullptr, g_tm, dil);
        mfma_gemm<1, KSR / 64, 6><<<384, 256, 0, stream>>>(
            wsr, g_tm, nullptr,
            bsk + (size_t)l * SCH, br + (size_t)l * RCH, nullptr, nullptr,
            skip, out_tm, outhf, 0);
    }

    reluconv_v<<<(T_LEN * 256 / 8) / 256, 256, 0, stream>>>(skip, skiphf);
    mfma_gemm<2, KPOST / 64, 2><<<128, 256, 0, stream>>>(
        Wp1_pk, skiphf, nullptr, bp1, nullptr, nullptr, nullptr,
        nullptr, nullptr, o1hf, 0);
    mfma_gemm<3, KPOST / 64, 2><<<128, 256, 0, stream>>>(
        Wp2_pk, o1hf, nullptr, bp2, nullptr, nullptr, nullptr,
        dout, nullptr, nullptr, 0);
}

// Round 14
// 1427.167 us; speedup vs baseline: 1.0243x; 1.0243x over previous
//
#include <hip/hip_runtime.h>
#include <hip/hip_bf16.h>
#include <math.h>
#include <stdint.h>

#define T_LEN 8192
#define RCH   512
#define SCH   256
#define QCH   256
#define ACH   28
#define NLAYER 30
#define KGATE 1088   // 512 tap0 + 512 tap1 + 64 aux (zero-padded from 28) = 17*64
#define KSR   512
#define KPOST 256

typedef _Float16 f16x8 __attribute__((ext_vector_type(8)));
typedef float    f32x4 __attribute__((ext_vector_type(4)));

#define SB0() __builtin_amdgcn_sched_barrier(0)

static __device__ __forceinline__ unsigned short f2h(float v) {
    _Float16 h = (_Float16)v;                 // RTN
    return *reinterpret_cast<unsigned short*>(&h);
}

// fast sigmoid: v_exp_f32 + rcp
static __device__ __forceinline__ float fsig(float x) {
    return __builtin_amdgcn_rcpf(1.f + __expf(-x));
}

// global -> LDS direct copy, 16B per lane, LDS dest wave-uniform base
#define G2L(SRC, DST) __builtin_amdgcn_global_load_lds(                        \
    (__attribute__((address_space(1))) void*)(const void*)(SRC),              \
    (__attribute__((address_space(3))) void*)(void*)(DST), 16, 0, 0)

// ---------------------------------------------------------------------------
// Gate dilated-tap pack, both taps per thread (reads 64B contiguous, uses all
// of it). 1024 m x 64 kgroups; grid.x = 256. Fragment map:
// dst[tile*512 + lane*8 + i] = A[mt*16+(lane&15)][kt*32+(lane>>4)*8+i],
// A row 2r = s-branch (Wds), 2r+1 = t-branch (Wdt); tap1 tile = tap0 tile+16.
__global__ void pack_gated_v(const float* __restrict__ Wds,
                             const float* __restrict__ Wdt,
                             unsigned short* __restrict__ dst) {
    int l = blockIdx.y;
    int c = blockIdx.x * 256 + threadIdx.x;
    int mlow = c & 15;
    int kg   = (c >> 4) & 63;                 // k0 = kg*8
    int mhi  = c >> 10;                       // 0..63
    int m  = mhi * 16 + mlow;
    int k0 = kg * 8;
    int br = m & 1, ch = m >> 1;
    const float* Wd = (br ? Wdt : Wds) + (size_t)l * RCH * RCH * 2
                    + ((size_t)ch * 512 + k0) * 2;
    unsigned short o0[8], o1[8];
    #pragma unroll
    for (int q = 0; q < 4; ++q) {
        float4 v = *(const float4*)(Wd + q * 4);
        o0[q * 2 + 0] = f2h(v.x); o1[q * 2 + 0] = f2h(v.y);
        o0[q * 2 + 1] = f2h(v.z); o1[q * 2 + 1] = f2h(v.w);
    }
    int mt   = m >> 4;
    int lane = ((k0 & 31) >> 3) * 16 + mlow;
    int kt0  = k0 >> 5;
    size_t base = (size_t)l * 1024 * KGATE;
    *(uint4*)&dst[base + (size_t)(mt * 34 + kt0)      * 512 + lane * 8] = *(uint4*)o0;
    *(uint4*)&dst[base + (size_t)(mt * 34 + kt0 + 16) * 512 + lane * 8] = *(uint4*)o1;
}

// Gate aux pack (tiles 32,33 of each mt): 1024 m x 8 kgroups = 8192 thr.
__global__ void pack_gatea_v(const float* __restrict__ Was,
                             const float* __restrict__ Wat,
                             unsigned short* __restrict__ dst) {
    int l = blockIdx.y;
    int c = blockIdx.x * 256 + threadIdx.x;   // grid.x = 32
    int mlow = c & 15;
    int kg   = (c >> 4) & 7;                  // a0 = kg*8
    int mhi  = c >> 7;                        // 0..63
    int m  = mhi * 16 + mlow;
    int a0 = kg * 8;
    int br = m & 1, ch = m >> 1;
    const float* Wa = (br ? Wat : Was) + (size_t)l * RCH * ACH + (size_t)ch * ACH;
    unsigned short o[8];
    #pragma unroll
    for (int i = 0; i < 8; ++i)
        o[i] = (a0 + i < ACH) ? f2h(Wa[a0 + i]) : (unsigned short)0;
    int mt   = m >> 4;
    int lane = ((a0 & 31) >> 3) * 16 + mlow;
    *(uint4*)&dst[(size_t)l * 1024 * KGATE
                  + (size_t)(mt * 34 + 32 + (a0 >> 5)) * 512 + lane * 8] = *(uint4*)o;
}

__global__ void pack_sr_v(const float* __restrict__ Wsk,
                          const float* __restrict__ Wr,
                          unsigned short* __restrict__ dst) {
    int l = blockIdx.y;
    int c = blockIdx.x * 256 + threadIdx.x;   // grid.x = 192
    int tile = c >> 6, lane = c & 63;
    int mt = tile >> 4, kt = tile & 15;       // KT32 = 16
    int m  = mt * 16 + (lane & 15);
    int k0 = kt * 32 + (lane >> 4) * 8;
    const float* row = (m < SCH) ? (Wsk + (size_t)l * SCH * RCH + (size_t)m * 512)
                                 : (Wr  + (size_t)l * RCH * RCH + (size_t)(m - SCH) * 512);
    float4 v0 = *(const float4*)(row + k0);
    float4 v1 = *(const float4*)(row + k0 + 4);
    unsigned short o[8] = { f2h(v0.x), f2h(v0.y), f2h(v0.z), f2h(v0.w),
                            f2h(v1.x), f2h(v1.y), f2h(v1.z), f2h(v1.w) };
    *(uint4*)&dst[(size_t)l * 768 * KSR + (size_t)tile * 512 + lane * 8] = *(uint4*)o;
}

__global__ void pack_post_v(const float* __restrict__ W,
                            unsigned short* __restrict__ dst) {
    int c = blockIdx.x * 256 + threadIdx.x;   // grid = 32
    int tile = c >> 6, lane = c & 63;
    int mt = tile >> 3, kt = tile & 7;        // KT32 = 8
    int m  = mt * 16 + (lane & 15);
    int k0 = kt * 32 + (lane >> 4) * 8;
    float4 v0 = *(const float4*)(W + (size_t)m * 256 + k0);
    float4 v1 = *(const float4*)(W + (size_t)m * 256 + k0 + 4);
    unsigned short o[8] = { f2h(v0.x), f2h(v0.y), f2h(v0.z), f2h(v0.w),
                            f2h(v1.x), f2h(v1.y), f2h(v1.z), f2h(v1.w) };
    *(uint4*)&dst[(size_t)tile * 512 + lane * 8] = *(uint4*)o;
}

// Wc [R][Q][2] -> WcT [Q][2][R]; 512*512/256 = 1024 WGs
__global__ void transpose_wc(const float* __restrict__ Wc,
                             float* __restrict__ WcT) {
    int idx = blockIdx.x * 256 + threadIdx.x;
    int r = idx >> 9;
    int qt = idx & 511;
    int q = qt >> 1, tap = qt & 1;
    WcT[(size_t)q * 1024 + tap * 512 + r] = Wc[(size_t)r * 512 + qt];
}

// ---------------------------------------------------------------------------
// embed: one wave per t; 8 channels/thread; coalesced via WcT.
__global__ void embed_v(const int* __restrict__ x,
                        const float* __restrict__ WcT,
                        const float* __restrict__ bc,
                        float* __restrict__ out_tm,
                        unsigned short* __restrict__ outhf) {
    int idx = blockIdx.x * 256 + threadIdx.x; // 2048 WGs
    int t = idx >> 6, rc = (idx & 63) * 8;
    int x1 = x[t];
    const float* w1 = WcT + (size_t)x1 * 1024 + 512 + rc;
    float4 a = *(const float4*)w1;
    float4 b = *(const float4*)(w1 + 4);
    float4 c0 = *(const float4*)(bc + rc);
    float4 c1 = *(const float4*)(bc + rc + 4);
    a.x += c0.x; a.y += c0.y; a.z += c0.z; a.w += c0.w;
    b.x += c1.x; b.y += c1.y; b.z += c1.z; b.w += c1.w;
    if (t > 0) {
        const float* w0 = WcT + (size_t)x[t - 1] * 1024 + rc;
        float4 d0 = *(const float4*)w0;
        float4 d1 = *(const float4*)(w0 + 4);
        a.x += d0.x; a.y += d0.y; a.z += d0.z; a.w += d0.w;
        b.x += d1.x; b.y += d1.y; b.z += d1.z; b.w += d1.w;
    }
    size_t o = (size_t)t * 512 + rc;
    *(float4*)&out_tm[o] = a;
    *(float4*)&out_tm[o + 4] = b;
    unsigned short p[8] = { f2h(a.x), f2h(a.y), f2h(a.z), f2h(a.w),
                            f2h(b.x), f2h(b.y), f2h(b.z), f2h(b.w) };
    *(uint4*)&outhf[o + 512 * 512] = *(uint4*)p;
}

// h -> time-major fp16 [8192][64], zero-padded channels 28..63
__global__ void packh_kernel(const float* __restrict__ h,
                             unsigned short* __restrict__ h_tm) {
    int idx = blockIdx.x * 256 + threadIdx.x;
    int t = idx >> 6, a = idx & 63;
    h_tm[idx] = f2h(a < ACH ? h[(size_t)a * T_LEN + t] : 0.f);
}

// relu(skip) -> fp16, 8/thread
__global__ void reluconv_v(const float* __restrict__ skip,
                           unsigned short* __restrict__ dst) {
    int idx = (blockIdx.x * 256 + threadIdx.x) * 8;
    float4 v0 = *(const float4*)(skip + idx);
    float4 v1 = *(const float4*)(skip + idx + 4);
    unsigned short o[8] = { f2h(fmaxf(v0.x, 0.f)), f2h(fmaxf(v0.y, 0.f)),
                            f2h(fmaxf(v0.z, 0.f)), f2h(fmaxf(v0.w, 0.f)),
                            f2h(fmaxf(v1.x, 0.f)), f2h(fmaxf(v1.y, 0.f)),
                            f2h(fmaxf(v1.z, 0.f)), f2h(fmaxf(v1.w, 0.f)) };
    *(uint4*)&dst[idx] = *(uint4*)o;
}

// ---------------------------------------------------------------------------
// MFMA GEMM, tile 128(M) x 128(N=time), BK=64, 4 waves in 4m x 1n layout:
// each wave owns 32 DISTINCT m-rows -> A fragments loaded from L2 exactly once
// per block. B LDS reads same-address across waves (broadcast, conflict-free).
// Pipeline (pinned order, R8-proven; R12 champion, 1427us):
//   per step: [4x G2L stage(kt+1)] SB0 [4x afr(kt+1)] SB0
//   [ds_read bfr(kt)] [setprio(1) MFMA(kt) setprio(0)]
//   SB0 "s_waitcnt vmcnt(4) lgkmcnt(0)" SB0 s_barrier
// FIFO at tail: [G2L(kt+1)x4 oldest | afr(kt+1)x4] -> vmcnt(4) retires exactly
// the G2Ls; afr(kt+1) crosses the barrier. lgkmcnt(0) closes rule-#18 hazard.
// XOR-swizzled LDS (both-sides, rule #21). Bijective XCD swizzle.
template<int MODE, int KT64, int MB>
__global__ __launch_bounds__(256) void mfma_gemm(
    const unsigned short* __restrict__ Apk,
    const unsigned short* __restrict__ B0,
    const unsigned short* __restrict__ B2,
    const float* __restrict__ bias0, const float* __restrict__ bias1,
    const float* __restrict__ bias2, const float* __restrict__ bias3,
    float* __restrict__ O0, float* __restrict__ O1,
    unsigned short* __restrict__ OB, int dil)
{
    constexpr int KT32 = KT64 * 2;
    constexpr int NWG = MB * 64;
    constexpr int CPX = NWG / 8;

    __shared__ unsigned short Bsm[2][128 * 64];       // 2 x 16 KB

    const int tid  = threadIdx.x;
    const int lane = tid & 63, wave = tid >> 6;

    const int bid = blockIdx.x;
    const int swz = (bid & 7) * CPX + (bid >> 3);     // bijective XCD swizzle
    const int mb  = swz % MB;
    const int tb  = swz / MB;
    const int m0  = mb * 128;
    const int t0  = tb * 128;

    const int kc   = ((lane & 7) ^ (lane >> 3)) * 8;  // pre-swizzled source chunk
    const int rsub = lane >> 3;

    const size_t mt0 = (size_t)(mb * 8) + wave * 2;   // wave owns 2 mt (32 rows)

    f32x4 acc[2][8];
    #pragma unroll
    for (int a = 0; a < 2; ++a)
        #pragma unroll
        for (int b = 0; b < 8; ++b) acc[a][b] = (f32x4){0.f, 0.f, 0.f, 0.f};

    f16x8 afrA[2][2], afrB[2][2], bfr[8][2];

    auto stage_tile = [&](int kt, int buf) {
        const int kb = kt * 64;
        #pragma unroll
        for (int j = 0; j < 4; ++j) {
            const int row = wave * 32 + j * 8 + rsub;
            const int tg  = t0 + row;
            const unsigned short* src;
            if constexpr (MODE == 0) {
                if (kb < 512)
                    src = B0 + (size_t)(512 + tg - dil) * 512 + kb + kc;
                else if (kb < 1024)
                    src = B0 + (size_t)(512 + tg) * 512 + (kb - 512) + kc;
                else
                    src = B2 + (size_t)tg * 64 + kc;
            } else if constexpr (MODE == 1) {
                src = B0 + (size_t)tg * 512 + kb + kc;
            } else {
                src = B0 + (size_t)tg * 256 + kb + kc;
            }
            G2L(src, &Bsm[buf][(wave * 4 + j) * 512]);
        }
    };

    auto load_afr = [&](int kt, f16x8 (&dst)[2][2]) {
        #pragma unroll
        for (int mi = 0; mi < 2; ++mi)
            #pragma unroll
            for (int ks = 0; ks < 2; ++ks)
                dst[mi][ks] = *(const f16x8*)(Apk +
                    ((mt0 + mi) * KT32 + (size_t)(kt * 2 + ks)) * 512 + lane * 8);
    };

    auto load_bfr = [&](int buf) {
        #pragma unroll
        for (int ni = 0; ni < 8; ++ni)
            #pragma unroll
            for (int ks = 0; ks < 2; ++ks) {
                const int trow = ni * 16 + (lane & 15);
                const int kch  = ks * 4 + (lane >> 4);
                const int sch  = kch ^ (lane & 7);
                bfr[ni][ks] = *(const f16x8*)&Bsm[buf][trow * 64 + sch * 8];
            }
    };

    auto do_mfma = [&](f16x8 (&A)[2][2]) {
        __builtin_amdgcn_s_setprio(1);
        #pragma unroll
        for (int mi = 0; mi < 2; ++mi)
            #pragma unroll
            for (int ni = 0; ni < 8; ++ni) {
                acc[mi][ni] = __builtin_amdgcn_mfma_f32_16x16x32_f16(
                    A[mi][0], bfr[ni][0], acc[mi][ni], 0, 0, 0);
                acc[mi][ni] = __builtin_amdgcn_mfma_f32_16x16x32_f16(
                    A[mi][1], bfr[ni][1], acc[mi][ni], 0, 0, 0);
            }
        __builtin_amdgcn_s_setprio(0);
    };

    // prologue: [4 G2L tile0] SB0 [4 afr0 loads] SB0 vmcnt(4) barrier
    stage_tile(0, 0);
    SB0();
    load_afr(0, afrA);
    SB0();
    asm volatile("s_waitcnt vmcnt(4)" ::: "memory");
    SB0();
    __builtin_amdgcn_s_barrier();

    #pragma unroll
    for (int kt = 0; kt < KT64; ++kt) {
        const int cur = kt & 1;
        if (kt + 1 < KT64) {
            stage_tile(kt + 1, cur ^ 1);              // 4 G2L, oldest group
            SB0();
            if (cur) load_afr(kt + 1, afrA);          // 4 reg loads, cross barrier
            else     load_afr(kt + 1, afrB);
            SB0();
        }
        load_bfr(cur);
        if (cur) do_mfma(afrB);
        else     do_mfma(afrA);
        if (kt + 1 < KT64) {
            SB0();
            asm volatile("s_waitcnt vmcnt(4) lgkmcnt(0)" ::: "memory");
            SB0();
            __builtin_amdgcn_s_barrier();
        }
    }

    // ---- epilogue ----
    const int rb0 = (lane >> 4) * 4;
    #pragma unroll
    for (int mi = 0; mi < 2; ++mi) {
        #pragma unroll
        for (int ni = 0; ni < 8; ++ni) {
            int m = m0 + wave * 32 + mi * 16 + rb0;   // multiple of 4
            int t = t0 + ni * 16 + (lane & 15);
            f32x4 v = acc[mi][ni];
            if constexpr (MODE == 0) {
                int c0 = m >> 1;                       // even
                float s0 = v.x + bias0[c0]     + bias2[c0];
                float tv0 = v.y + bias1[c0]     + bias3[c0];
                float s1 = v.z + bias0[c0 + 1] + bias2[c0 + 1];
                float tv1 = v.w + bias1[c0 + 1] + bias3[c0 + 1];
                // g = sigmoid(s) * tanh(t);  tanh(t) = 2*sigmoid(2t) - 1
                float g0 = fsig(s0) * (2.f * fsig(2.f * tv0) - 1.f);
                float g1 = fsig(s1) * (2.f * fsig(2.f * tv1) - 1.f);
                unsigned int p = (unsigned int)f2h(g0) | ((unsigned int)f2h(g1) << 16);
                *(unsigned int*)&OB[(size_t)t * 512 + c0] = p;
            } else if constexpr (MODE == 1) {
                if (m < SCH) {
                    float4* p = (float4*)&O0[(size_t)t * 256 + m];
                    float4 o = *p;
                    o.x += v.x + bias0[m + 0];
                    o.y += v.y + bias0[m + 1];
                    o.z += v.z + bias0[m + 2];
                    o.w += v.w + bias0[m + 3];
                    *p = o;
                } else {
                    int c = m - SCH;
                    float4* p = (float4*)&O1[(size_t)t * 512 + c];
                    float4 o = *p;
                    o.x += v.x + bias1[c + 0];
                    o.y += v.y + bias1[c + 1];
                    o.z += v.z + bias1[c + 2];
                    o.w += v.w + bias1[c + 3];
                    *p = o;
                    uint2 pk;
                    pk.x = (unsigned int)f2h(o.x) | ((unsigned int)f2h(o.y) << 16);
                    pk.y = (unsigned int)f2h(o.z) | ((unsigned int)f2h(o.w) << 16);
                    *(uint2*)&OB[(size_t)(512 + t) * 512 + c] = pk;
                }
            } else if constexpr (MODE == 2) {
                float o0 = fmaxf(v.x + bias0[m + 0], 0.f);
                float o1 = fmaxf(v.y + bias0[m + 1], 0.f);
                float o2 = fmaxf(v.z + bias0[m + 2], 0.f);
                float o3 = fmaxf(v.w + bias0[m + 3], 0.f);
                uint2 pk;
                pk.x = (unsigned int)f2h(o0) | ((unsigned int)f2h(o1) << 16);
                pk.y = (unsigned int)f2h(o2) | ((unsigned int)f2h(o3) << 16);
                *(uint2*)&OB[(size_t)t * 256 + m] = pk;
            } else {
                float4 o;
                o.x = v.x + bias0[m + 0];
                o.y = v.y + bias0[m + 1];
                o.z = v.z + bias0[m + 2];
                o.w = v.w + bias0[m + 3];
                *(float4*)&O0[(size_t)t * 256 + m] = o;
            }
        }
    }
}

// ---------------------------------------------------------------------------
extern "C" void kernel_launch(void* const* d_in, const int* in_sizes, int n_in,
                              void* d_out, int out_size, void* d_ws, size_t ws_size,
                              hipStream_t stream) {
    const int*   x   = (const int*)  d_in[0];
    const float* h   = (const float*)d_in[1];
    const float* Wc  = (const float*)d_in[2];
    const float* bc  = (const float*)d_in[3];
    const float* Wds = (const float*)d_in[4];
    const float* bds = (const float*)d_in[5];
    const float* Wdt = (const float*)d_in[6];
    const float* bdt = (const float*)d_in[7];
    const float* Was = (const float*)d_in[8];
    const float* bas = (const float*)d_in[9];
    const float* Wat = (const float*)d_in[10];
    const float* bat = (const float*)d_in[11];
    const float* Wsk = (const float*)d_in[12];
    const float* bsk = (const float*)d_in[13];
    const float* Wr  = (const float*)d_in[14];
    const float* br  = (const float*)d_in[15];
    const float* Wp1 = (const float*)d_in[16];
    const float* bp1 = (const float*)d_in[17];
    const float* Wp2 = (const float*)d_in[18];
    const float* bp2 = (const float*)d_in[19];
    float* dout = (float*)d_out;

    // ---- workspace layout (bytes) ----
    const size_t WG_EL  = (size_t)1024 * KGATE;
    const size_t WSR_EL = (size_t)768 * KSR;
    char* w = (char*)d_ws;
    float*          out_tm = (float*)w;               w += (size_t)T_LEN * 512 * 4;
    unsigned short* outhf  = (unsigned short*)w;      w += (size_t)(T_LEN + 512) * 512 * 2;
    unsigned short* g_tm   = (unsigned short*)w;      w += (size_t)T_LEN * 512 * 2;
    unsigned short* h_tm   = (unsigned short*)w;      w += (size_t)T_LEN * 64 * 2;
    unsigned short* skiphf = (unsigned short*)w;      w += (size_t)T_LEN * 256 * 2;
    unsigned short* o1hf   = (unsigned short*)w;      w += (size_t)T_LEN * 256 * 2;
    unsigned short* Wp1_pk = (unsigned short*)w;      w += (size_t)256 * 256 * 2;
    unsigned short* Wp2_pk = (unsigned short*)w;      w += (size_t)256 * 256 * 2;
    float*          WcT    = (float*)w;               w += (size_t)QCH * 2 * RCH * 4;   // 1 MB
    unsigned short* Wg_pk  = (unsigned short*)w;
    size_t used_base = (size_t)((char*)Wg_pk - (char*)d_ws);
    size_t need_bulk = used_base + (WG_EL + WSR_EL) * NLAYER * 2;
    const bool bulk = ws_size >= need_bulk;
    unsigned short* Wsr_pk = Wg_pk + (bulk ? WG_EL * NLAYER : WG_EL);
    float* skip = dout;                               // [8192][256] f32 accumulator

    hipMemsetAsync(skip, 0, (size_t)T_LEN * 256 * 4, stream);
    hipMemsetAsync(outhf, 0, (size_t)512 * 512 * 2, stream);

    transpose_wc<<<1024, 256, 0, stream>>>(Wc, WcT);
    embed_v<<<(T_LEN * 64) / 256, 256, 0, stream>>>(x, WcT, bc, out_tm, outhf);
    packh_kernel<<<(T_LEN * 64) / 256, 256, 0, stream>>>(h, h_tm);
    pack_post_v<<<32, 256, 0, stream>>>(Wp1, Wp1_pk);
    pack_post_v<<<32, 256, 0, stream>>>(Wp2, Wp2_pk);

    if (bulk) {
        pack_gated_v<<<dim3(256, NLAYER), 256, 0, stream>>>(Wds, Wdt, Wg_pk);
        pack_gatea_v<<<dim3(32, NLAYER), 256, 0, stream>>>(Was, Wat, Wg_pk);
        pack_sr_v<<<dim3(192, NLAYER), 256, 0, stream>>>(Wsk, Wr, Wsr_pk);
    }

    for (int l = 0; l < NLAYER; ++l) {
        int dil = 1 << (l % 10);
        const unsigned short* wg;
        const unsigned short* wsr;
        if (bulk) {
            wg  = Wg_pk  + (size_t)l * WG_EL;
            wsr = Wsr_pk + (size_t)l * WSR_EL;
        } else {
            pack_gated_v<<<dim3(256, 1), 256, 0, stream>>>(
                Wds + (size_t)l * RCH * RCH * 2, Wdt + (size_t)l * RCH * RCH * 2, Wg_pk);
            pack_gatea_v<<<dim3(32, 1), 256, 0, stream>>>(
                Was + (size_t)l * RCH * ACH, Wat + (size_t)l * RCH * ACH, Wg_pk);
            pack_sr_v<<<dim3(192, 1), 256, 0, stream>>>(
                Wsk + (size_t)l * SCH * RCH, Wr + (size_t)l * RCH * RCH, Wsr_pk);
            wg = Wg_pk; wsr = Wsr_pk;
        }
        mfma_gemm<0, KGATE / 64, 8><<<512, 256, 0, stream>>>(
            wg, outhf, h_tm,
            bds + (size_t)l * RCH, bdt + (size_t)l * RCH,
            bas + (size_t)l * RCH, bat + (size_t)l * RCH,
            nullptr, nullptr, g_tm, dil);
        mfma_gemm<1, KSR / 64, 6><<<384, 256, 0, stream>>>(
            wsr, g_tm, nullptr,
            bsk + (size_t)l * SCH, br + (size_t)l * RCH, nullptr, nullptr,
            skip, out_tm, outhf, 0);
    }

    reluconv_v<<<(T_LEN * 256 / 8) / 256, 256, 0, stream>>>(skip, skiphf);
    mfma_gemm<2, KPOST / 64, 2><<<128, 256, 0, stream>>>(
        Wp1_pk, skiphf, nullptr, bp1, nullptr, nullptr, nullptr,
        nullptr, nullptr, o1hf, 0);
    mfma_gemm<3, KPOST / 64, 2><<<128, 256, 0, stream>>>(
        Wp2_pk, o1hf, nullptr, bp2, nullptr, nullptr, nullptr,
        dout, nullptr, nullptr, 0);
}